// Round 3
// baseline (123.785 us; speedup 1.0000x reference)
//
#include <hip/hip_runtime.h>
#include <math.h>

#define B_BAGS 512
#define N_REL  128
#define D_DIM  768
#define M_PAD  24      // max actual bag size (sizes in [8,25))
#define NCHUNK 8       // split-K factor for h_gemm
#define SPC    3       // K-steps (of 32) per chunk: 8*3*32 = 768

typedef __attribute__((ext_vector_type(8))) short  bf16x8;
typedef __attribute__((ext_vector_type(4))) float  f32x4;

// pack truncated-bf16 of (f0,f1) -> one uint (low short = bf16(f0))
__device__ inline unsigned pack_hi(float f0, float f1) {
    return __builtin_amdgcn_perm(__float_as_uint(f1), __float_as_uint(f0), 0x07060302u);
}
__device__ inline float trunc_res(float f) {   // f - bf16_trunc(f)
    return f - __uint_as_float(__float_as_uint(f) & 0xFFFF0000u);
}

// ---------------------------------------------------------------------------
// K1: build fragment-ordered bf16 hi/lo of W for the MFMA B-operand.
// Layout (shorts): Bfrag[s][tile][p][lane][8],  s<24, tile<8, p in {hi,lo}.
// Element = W[n][k],  n = tile*16 + (lane&15),  k = s*32 + (lane>>4)*8 + j.
// (validated in round 2)
// ---------------------------------------------------------------------------
__global__ void build_bfrag(const float* __restrict__ W, unsigned* __restrict__ Bfrag) {
    int flat = blockIdx.x * 256 + threadIdx.x;     // 0..12287
    int lane = flat & 63;
    int tile = (flat >> 6) & 7;
    int s    = flat >> 9;                          // 0..23
    int n  = tile * 16 + (lane & 15);
    int k0 = s * 32 + (lane >> 4) * 8;
    const float* src = &W[n * D_DIM + k0];
    float f[8];
    #pragma unroll
    for (int j = 0; j < 8; ++j) f[j] = src[j];
    unsigned hi[4], lo[4];
    #pragma unroll
    for (int q = 0; q < 4; ++q) {
        hi[q] = pack_hi(f[2*q], f[2*q+1]);
        lo[q] = pack_hi(trunc_res(f[2*q]), trunc_res(f[2*q+1]));
    }
    unsigned base = (unsigned)(((s * 8 + tile) * 2) * 64 + lane) * 4;   // uints
    *(uint4*)&Bfrag[base]          = make_uint4(hi[0], hi[1], hi[2], hi[3]);
    *(uint4*)&Bfrag[base + 64 * 4] = make_uint4(lo[0], lo[1], lo[2], lo[3]);
}

// ---------------------------------------------------------------------------
// K2: dense H = rep @ W^T  (nsum x 128), bf16x3 MFMA, split-K via atomics.
// One wave per block: 16 rows x 128 cols x 96 of K. No LDS, no barriers.
// grid = (ceil(nsum/16), NCHUNK)
// ---------------------------------------------------------------------------
__global__ __launch_bounds__(64) void h_gemm(
    const float*          __restrict__ rep,
    const unsigned short* __restrict__ Bfrag,
    float*                __restrict__ H,
    int nsum)
{
    const int lane  = threadIdx.x;     // 0..63
    const int strip = blockIdx.x;      // 16-row strip
    const int chunk = blockIdx.y;      // K chunk (96 wide)

    // A-fragment row for 16x16x32: row = lane&15, k-group = lane>>4
    int row = strip * 16 + (lane & 15);
    row = (row > nsum - 1) ? (nsum - 1) : row;
    const float* rp = &rep[(size_t)row * D_DIM + (lane >> 4) * 8];

    f32x4 acc[8][2];   // [n-tile][0]=hi*hi, [1]=hi*lo + lo*hi
    #pragma unroll
    for (int t = 0; t < 8; ++t) {
        acc[t][0] = f32x4{0.f, 0.f, 0.f, 0.f};
        acc[t][1] = f32x4{0.f, 0.f, 0.f, 0.f};
    }

    #pragma unroll
    for (int s = 0; s < SPC; ++s) {
        const int gs = chunk * SPC + s;            // global K-step 0..23
        const float4 v0 = *(const float4*)&rp[gs * 32];
        const float4 v1 = *(const float4*)&rp[gs * 32 + 4];
        union { unsigned u[4]; bf16x8 v; } ah, al;
        ah.u[0] = pack_hi(v0.x, v0.y);
        ah.u[1] = pack_hi(v0.z, v0.w);
        ah.u[2] = pack_hi(v1.x, v1.y);
        ah.u[3] = pack_hi(v1.z, v1.w);
        al.u[0] = pack_hi(trunc_res(v0.x), trunc_res(v0.y));
        al.u[1] = pack_hi(trunc_res(v0.z), trunc_res(v0.w));
        al.u[2] = pack_hi(trunc_res(v1.x), trunc_res(v1.y));
        al.u[3] = pack_hi(trunc_res(v1.z), trunc_res(v1.w));

        #pragma unroll
        for (int tile = 0; tile < 8; ++tile) {
            const int tid8 = gs * 8 + tile;
            const bf16x8 bh = *(const bf16x8*)&Bfrag[((size_t)(tid8 * 2 + 0) * 64 + lane) * 8];
            const bf16x8 bl = *(const bf16x8*)&Bfrag[((size_t)(tid8 * 2 + 1) * 64 + lane) * 8];
            acc[tile][0] = __builtin_amdgcn_mfma_f32_16x16x32_bf16(ah.v, bh, acc[tile][0], 0, 0, 0);
            acc[tile][1] = __builtin_amdgcn_mfma_f32_16x16x32_bf16(ah.v, bl, acc[tile][1], 0, 0, 0);
            acc[tile][1] = __builtin_amdgcn_mfma_f32_16x16x32_bf16(al.v, bh, acc[tile][1], 0, 0, 0);
        }
    }

    // C/D layout: col = lane&15, row = (lane>>4)*4 + reg  (validated r2)
    const int rowb = strip * 16 + (lane >> 4) * 4;
    const int colb = lane & 15;
    #pragma unroll
    for (int tile = 0; tile < 8; ++tile) {
        #pragma unroll
        for (int r = 0; r < 4; ++r) {
            atomicAdd(&H[(size_t)(rowb + r) * N_REL + tile * 16 + colb],
                      acc[tile][0][r] + acc[tile][1][r]);
        }
    }
}

// ---------------------------------------------------------------------------
// K3: per-bag phase 2. G = H[start:start+size], masked softmax over m,
// online softmax over k of full = sm@G + bias, output diagonal prob.
// (structure validated in rounds 1-2; m-extent now 24 with zero-padded rows)
// ---------------------------------------------------------------------------
__global__ __launch_bounds__(256, 2) void bag_out(
    const float* __restrict__ H,
    const float* __restrict__ bias,
    const int*   __restrict__ scope,
    float*       __restrict__ out)
{
    __shared__ float Gs[M_PAD][N_REL + 4];       // 24 x 132
    __shared__ float redM[256], redL[256], redD[256];

    const int t = threadIdx.x;
    const int b = blockIdx.x;
    const int start = scope[2 * b];
    const int size  = scope[2 * b + 1] - start;  // in [8, 25)

    // stage H rows (zero-fill padded rows so 0*0 stays clean in the k-loop)
    #pragma unroll
    for (int i = 0; i < 3; ++i) {
        int flat = i * 256 + t;                  // 0..767 = 24 rows x 32 float4
        int m  = flat >> 5;
        int c4 = flat & 31;
        float4 v = make_float4(0.f, 0.f, 0.f, 0.f);
        if (m < size) v = *(const float4*)&H[(size_t)(start + m) * N_REL + c4 * 4];
        *(float4*)&Gs[m][c4 * 4] = v;
    }
    __syncthreads();

    const int n = t & 127;
    const int h = t >> 7;

    // masked softmax over m of column Gs[:, n]
    float sm[M_PAD];
    float gmax = -INFINITY;
    #pragma unroll
    for (int m = 0; m < M_PAD; ++m) {
        float g = Gs[m][n];
        sm[m] = g;
        if (m < size) gmax = fmaxf(gmax, g);
    }
    float ssum = 0.f;
    #pragma unroll
    for (int m = 0; m < M_PAD; ++m) {
        float e = __expf(sm[m] - gmax);
        e = (m < size) ? e : 0.f;
        sm[m] = e;
        ssum += e;
    }
    const float inv = 1.f / ssum;
    #pragma unroll
    for (int m = 0; m < M_PAD; ++m) sm[m] *= inv;

    // online softmax over this thread's k-half of full[n][k] = bias[k] + sm.G[:,k]
    float mx = -INFINITY, l = 0.f, sd = 0.f;
    const int kbase = h * 64;
    #pragma unroll 4
    for (int kk = 0; kk < 64; kk += 4) {
        const int k = kbase + kk;
        float4 b4 = *(const float4*)&bias[k];
        float s0 = b4.x, s1 = b4.y, s2 = b4.z, s3 = b4.w;
        #pragma unroll
        for (int m = 0; m < M_PAD; ++m) {
            const float4 g = *(const float4*)&Gs[m][k];   // same-addr broadcast
            const float w = sm[m];
            s0 += w * g.x; s1 += w * g.y; s2 += w * g.z; s3 += w * g.w;
        }
        float s[4] = {s0, s1, s2, s3};
        #pragma unroll
        for (int j = 0; j < 4; ++j) {
            const float sj = s[j];
            const float mnew = fmaxf(mx, sj);
            l = l * __expf(mx - mnew) + __expf(sj - mnew);
            mx = mnew;
            sd = (k + j == n) ? sj : sd;
        }
    }

    // merge the two k-halves via LDS
    redM[t] = mx; redL[t] = l; redD[t] = sd;
    __syncthreads();
    if (t < 128) {
        const float m0 = redM[t],       l0 = redL[t],       d0 = redD[t];
        const float m1 = redM[t + 128], l1 = redL[t + 128], d1 = redD[t + 128];
        const float M  = fmaxf(m0, m1);
        const float L  = l0 * __expf(m0 - M) + l1 * __expf(m1 - M);
        const float sdiag = (t < 64) ? d0 : d1;   // k==n lives in half n/64
        out[b * N_REL + t] = __expf(sdiag - M) / L;
    }
}

// ---------------------------------------------------------------------------
extern "C" void kernel_launch(void* const* d_in, const int* in_sizes, int n_in,
                              void* d_out, int out_size, void* d_ws, size_t ws_size,
                              hipStream_t stream) {
    const float* rep   = (const float*)d_in[0];
    const float* W     = (const float*)d_in[1];
    const float* bias  = (const float*)d_in[2];
    const int*   scope = (const int*)d_in[3];

    const int nsum   = in_sizes[0] / D_DIM;
    const int strips = (nsum + 15) >> 4;

    unsigned* Bfrag = (unsigned*)d_ws;                       // 393216 B
    float*    H     = (float*)((char*)d_ws + 393216);        // strips*16*128 fp32

    build_bfrag<<<48, 256, 0, stream>>>(W, Bfrag);
    hipMemsetAsync(H, 0, (size_t)strips * 16 * N_REL * sizeof(float), stream);
    h_gemm<<<dim3(strips, NCHUNK), 64, 0, stream>>>(
        rep, (const unsigned short*)Bfrag, H, nsum);
    bag_out<<<B_BAGS, 256, 0, stream>>>(H, bias, scope, (float*)d_out);
}

// Round 4
// 102.299 us; speedup vs baseline: 1.2100x; 1.2100x over previous
//
#include <hip/hip_runtime.h>
#include <math.h>

#define B_BAGS 512
#define N_REL  128
#define D_DIM  768
#define M_PAD  24      // max actual bag size (sizes in [8,25))
#define NCHUNK 4       // split-K partial buffers for h_gemm
#define SPC    6       // K-steps (of 32) per chunk: 4*6*32 = 768

typedef __attribute__((ext_vector_type(8))) short  bf16x8;
typedef __attribute__((ext_vector_type(4))) float  f32x4;

// pack truncated-bf16 of (f0,f1) -> one uint (low short = bf16(f0))
__device__ inline unsigned pack_hi(float f0, float f1) {
    return __builtin_amdgcn_perm(__float_as_uint(f1), __float_as_uint(f0), 0x07060302u);
}
__device__ inline float trunc_res(float f) {   // f - bf16_trunc(f)
    return f - __uint_as_float(__float_as_uint(f) & 0xFFFF0000u);
}

// ---------------------------------------------------------------------------
// K1: fragment-ordered bf16 hi/lo of W for the MFMA B-operand (validated r2/r3).
// Element = W[n][k], n = tile*16 + (lane&15), k = s*32 + (lane>>4)*8 + j.
// ---------------------------------------------------------------------------
__global__ void build_bfrag(const float* __restrict__ W, unsigned* __restrict__ Bfrag) {
    int flat = blockIdx.x * 256 + threadIdx.x;     // 0..12287
    int lane = flat & 63;
    int tile = (flat >> 6) & 7;
    int s    = flat >> 9;                          // 0..23
    int n  = tile * 16 + (lane & 15);
    int k0 = s * 32 + (lane >> 4) * 8;
    const float* src = &W[n * D_DIM + k0];
    float f[8];
    #pragma unroll
    for (int j = 0; j < 8; ++j) f[j] = src[j];
    unsigned hi[4], lo[4];
    #pragma unroll
    for (int q = 0; q < 4; ++q) {
        hi[q] = pack_hi(f[2*q], f[2*q+1]);
        lo[q] = pack_hi(trunc_res(f[2*q]), trunc_res(f[2*q+1]));
    }
    unsigned base = (unsigned)(((s * 8 + tile) * 2) * 64 + lane) * 4;
    *(uint4*)&Bfrag[base]          = make_uint4(hi[0], hi[1], hi[2], hi[3]);
    *(uint4*)&Bfrag[base + 64 * 4] = make_uint4(lo[0], lo[1], lo[2], lo[3]);
}

// ---------------------------------------------------------------------------
// K2: dense H = rep @ W^T, bf16x3 MFMA, split-K into NCHUNK partial buffers
// with PLAIN stores (no atomics, no memset). grid = (strips, NCHUNK), 64 thr.
// ---------------------------------------------------------------------------
__global__ __launch_bounds__(64) void h_gemm(
    const float*          __restrict__ rep,
    const unsigned short* __restrict__ Bfrag,
    float*                __restrict__ Hp,     // NCHUNK buffers of hstride floats
    int nsum, int hstride)
{
    const int lane  = threadIdx.x;
    const int strip = blockIdx.x;
    const int chunk = blockIdx.y;

    int row = strip * 16 + (lane & 15);
    row = (row > nsum - 1) ? (nsum - 1) : row;
    const float* rp = &rep[(size_t)row * D_DIM + (lane >> 4) * 8];

    f32x4 acc[8][2];
    #pragma unroll
    for (int t = 0; t < 8; ++t) {
        acc[t][0] = f32x4{0.f, 0.f, 0.f, 0.f};
        acc[t][1] = f32x4{0.f, 0.f, 0.f, 0.f};
    }

    #pragma unroll
    for (int s = 0; s < SPC; ++s) {
        const int gs = chunk * SPC + s;            // global K-step 0..23
        const float4 v0 = *(const float4*)&rp[gs * 32];
        const float4 v1 = *(const float4*)&rp[gs * 32 + 4];
        union { unsigned u[4]; bf16x8 v; } ah, al;
        ah.u[0] = pack_hi(v0.x, v0.y);
        ah.u[1] = pack_hi(v0.z, v0.w);
        ah.u[2] = pack_hi(v1.x, v1.y);
        ah.u[3] = pack_hi(v1.z, v1.w);
        al.u[0] = pack_hi(trunc_res(v0.x), trunc_res(v0.y));
        al.u[1] = pack_hi(trunc_res(v0.z), trunc_res(v0.w));
        al.u[2] = pack_hi(trunc_res(v1.x), trunc_res(v1.y));
        al.u[3] = pack_hi(trunc_res(v1.z), trunc_res(v1.w));

        #pragma unroll
        for (int tile = 0; tile < 8; ++tile) {
            const int tid8 = gs * 8 + tile;
            const bf16x8 bh = *(const bf16x8*)&Bfrag[((size_t)(tid8 * 2 + 0) * 64 + lane) * 8];
            const bf16x8 bl = *(const bf16x8*)&Bfrag[((size_t)(tid8 * 2 + 1) * 64 + lane) * 8];
            acc[tile][0] = __builtin_amdgcn_mfma_f32_16x16x32_bf16(ah.v, bh, acc[tile][0], 0, 0, 0);
            acc[tile][1] = __builtin_amdgcn_mfma_f32_16x16x32_bf16(ah.v, bl, acc[tile][1], 0, 0, 0);
            acc[tile][1] = __builtin_amdgcn_mfma_f32_16x16x32_bf16(al.v, bh, acc[tile][1], 0, 0, 0);
        }
    }

    float* H = Hp + (size_t)chunk * hstride;
    const int rowb = strip * 16 + (lane >> 4) * 4;   // C/D: col=lane&15, row=(lane>>4)*4+r
    const int colb = lane & 15;
    #pragma unroll
    for (int tile = 0; tile < 8; ++tile)
        #pragma unroll
        for (int r = 0; r < 4; ++r)
            H[(size_t)(rowb + r) * N_REL + tile * 16 + colb] =
                acc[tile][0][r] + acc[tile][1][r];
}

// ---------------------------------------------------------------------------
// K3: per-bag phase 2, MFMA-based.
//   stage1: Gs = sum of 4 H partials (zero-padded rows)
//   stage1b/2: build bf16 hi/lo fragments of G (B-op) and softmaxed SM (A-op)
//   stage3: full = SM@G via bf16x3 MFMA (48 MFMA/wave)
//   stage4: full logits -> Fs (LDS, overlays fragment region)
//   stage5: r1-validated online softmax over k + diag + merge
// ---------------------------------------------------------------------------
__global__ __launch_bounds__(256, 2) void bag_out(
    const float* __restrict__ Hp, int hstride,
    const float* __restrict__ bias,
    const int*   __restrict__ scope,
    float*       __restrict__ out)
{
    // LDS union: [Gs 12672][Gfrag 16384][SMfrag 16384] then overlaid by
    // [Fs 67584][redM/L/D 3072] = 70656 B total -> 2 blocks/CU.
    __shared__ char smem[70656];
    float    (*Gs)[132] = (float(*)[132])smem;                 // 24 x 132
    unsigned* Gfrag     = (unsigned*)(smem + 12672);           // [ct][p][lane][4]
    unsigned* SMfrag    = (unsigned*)(smem + 12672 + 16384);   // [nt][p][lane][4]
    float    (*Fs)[132] = (float(*)[132])smem;                 // 128 x 132 (overlay)
    float*    redM      = (float*)(smem + 67584);
    float*    redL      = redM + 256;
    float*    redD      = redL + 256;

    const int t = threadIdx.x;
    const int b = blockIdx.x;
    const int start = scope[2 * b];
    const int size  = scope[2 * b + 1] - start;     // in [8, 25)

    // ---- stage 1: Gs = sum of partials, zero-padded rows ----
    #pragma unroll
    for (int i = 0; i < 3; ++i) {
        int flat = i * 256 + t;                     // 768 = 24 rows x 32 float4
        int m  = flat >> 5;
        int c4 = flat & 31;
        float4 v = make_float4(0.f, 0.f, 0.f, 0.f);
        if (m < size) {
            const float* p = &Hp[(size_t)(start + m) * N_REL + c4 * 4];
            const float4 a0 = *(const float4*)(p);
            const float4 a1 = *(const float4*)(p + (size_t)hstride);
            const float4 a2 = *(const float4*)(p + (size_t)hstride * 2);
            const float4 a3 = *(const float4*)(p + (size_t)hstride * 3);
            v = make_float4(a0.x + a1.x + a2.x + a3.x,
                            a0.y + a1.y + a2.y + a3.y,
                            a0.z + a1.z + a2.z + a3.z,
                            a0.w + a1.w + a2.w + a3.w);
        }
        *(float4*)&Gs[m][c4 * 4] = v;
    }
    __syncthreads();

    // ---- stage 1b: Gfrag (B-operand): B[k=m][col=c], lane=kg*16+(c&15) ----
    {
        const int c  = t & 127;
        const int ct = c >> 4;
        const int kg0 = t >> 7;                     // 0 or 1
        #pragma unroll
        for (int kk = 0; kk < 2; ++kk) {
            const int kg = kg0 + kk * 2;            // 0..3 -> m = kg*8+j
            unsigned hi[4], lo[4];
            #pragma unroll
            for (int q = 0; q < 4; ++q) {
                const int m0 = kg * 8 + q * 2;
                const float f0 = (m0     < M_PAD) ? Gs[m0][c]     : 0.f;
                const float f1 = (m0 + 1 < M_PAD) ? Gs[m0 + 1][c] : 0.f;
                hi[q] = pack_hi(f0, f1);
                lo[q] = pack_hi(trunc_res(f0), trunc_res(f1));
            }
            const int lanef = kg * 16 + (c & 15);
            *(uint4*)&Gfrag[((ct * 2 + 0) * 64 + lanef) * 4] = make_uint4(hi[0], hi[1], hi[2], hi[3]);
            *(uint4*)&Gfrag[((ct * 2 + 1) * 64 + lanef) * 4] = make_uint4(lo[0], lo[1], lo[2], lo[3]);
        }
    }

    // ---- stage 2: masked softmax per column n -> SMfrag (A-operand) ----
    if (t < 128) {
        const int n = t;
        float g[M_PAD];
        float gmax = -INFINITY;
        #pragma unroll
        for (int m = 0; m < M_PAD; ++m) {
            g[m] = Gs[m][n];
            if (m < size) gmax = fmaxf(gmax, g[m]);
        }
        float ssum = 0.f;
        #pragma unroll
        for (int m = 0; m < M_PAD; ++m) {
            float e = __expf(g[m] - gmax);
            e = (m < size) ? e : 0.f;
            g[m] = e;
            ssum += e;
        }
        const float inv = 1.f / ssum;
        #pragma unroll
        for (int m = 0; m < M_PAD; ++m) g[m] *= inv;

        const int ntile = n >> 4;
        #pragma unroll
        for (int kg = 0; kg < 4; ++kg) {            // A: row=n, k = kg*8+j
            unsigned hi[4], lo[4];
            #pragma unroll
            for (int q = 0; q < 4; ++q) {
                const int m0 = kg * 8 + q * 2;
                const float f0 = (m0     < M_PAD) ? g[m0]     : 0.f;
                const float f1 = (m0 + 1 < M_PAD) ? g[m0 + 1] : 0.f;
                hi[q] = pack_hi(f0, f1);
                lo[q] = pack_hi(trunc_res(f0), trunc_res(f1));
            }
            const int lanef = kg * 16 + (n & 15);
            *(uint4*)&SMfrag[((ntile * 2 + 0) * 64 + lanef) * 4] = make_uint4(hi[0], hi[1], hi[2], hi[3]);
            *(uint4*)&SMfrag[((ntile * 2 + 1) * 64 + lanef) * 4] = make_uint4(lo[0], lo[1], lo[2], lo[3]);
        }
    }
    __syncthreads();

    // ---- stage 3: full = SM @ G  (bf16x3) ----
    const int wv   = t >> 6;
    const int lane = t & 63;
    f32x4 acc[2][8];
    #pragma unroll
    for (int tt = 0; tt < 2; ++tt)
        #pragma unroll
        for (int ct = 0; ct < 8; ++ct)
            acc[tt][ct] = f32x4{0.f, 0.f, 0.f, 0.f};

    const bf16x8 ah0 = *(const bf16x8*)&SMfrag[(((wv * 2 + 0) * 2 + 0) * 64 + lane) * 4];
    const bf16x8 al0 = *(const bf16x8*)&SMfrag[(((wv * 2 + 0) * 2 + 1) * 64 + lane) * 4];
    const bf16x8 ah1 = *(const bf16x8*)&SMfrag[(((wv * 2 + 1) * 2 + 0) * 64 + lane) * 4];
    const bf16x8 al1 = *(const bf16x8*)&SMfrag[(((wv * 2 + 1) * 2 + 1) * 64 + lane) * 4];
    #pragma unroll
    for (int ct = 0; ct < 8; ++ct) {
        const bf16x8 bh = *(const bf16x8*)&Gfrag[((ct * 2 + 0) * 64 + lane) * 4];
        const bf16x8 bl = *(const bf16x8*)&Gfrag[((ct * 2 + 1) * 64 + lane) * 4];
        acc[0][ct] = __builtin_amdgcn_mfma_f32_16x16x32_bf16(ah0, bh, acc[0][ct], 0, 0, 0);
        acc[0][ct] = __builtin_amdgcn_mfma_f32_16x16x32_bf16(ah0, bl, acc[0][ct], 0, 0, 0);
        acc[0][ct] = __builtin_amdgcn_mfma_f32_16x16x32_bf16(al0, bh, acc[0][ct], 0, 0, 0);
        acc[1][ct] = __builtin_amdgcn_mfma_f32_16x16x32_bf16(ah1, bh, acc[1][ct], 0, 0, 0);
        acc[1][ct] = __builtin_amdgcn_mfma_f32_16x16x32_bf16(ah1, bl, acc[1][ct], 0, 0, 0);
        acc[1][ct] = __builtin_amdgcn_mfma_f32_16x16x32_bf16(al1, bh, acc[1][ct], 0, 0, 0);
    }
    __syncthreads();   // all frag reads done before Fs overlays them

    // ---- stage 4: scatter logits to Fs (C/D: col=lane&15, row=(lane>>4)*4+r) ----
    #pragma unroll
    for (int tt = 0; tt < 2; ++tt) {
        const int nrow = (wv * 2 + tt) * 16 + (lane >> 4) * 4;
        #pragma unroll
        for (int ct = 0; ct < 8; ++ct) {
            const int c = ct * 16 + (lane & 15);
            #pragma unroll
            for (int r = 0; r < 4; ++r) Fs[nrow + r][c] = acc[tt][ct][r];
        }
    }
    __syncthreads();

    // ---- stage 5: online softmax over k + diag + merge (r1-validated) ----
    const int n = t & 127;
    const int h = t >> 7;
    float mx = -INFINITY, l = 0.f, sd = 0.f;
    const int kbase = h * 64;
    #pragma unroll 4
    for (int kk = 0; kk < 64; kk += 4) {
        const int k = kbase + kk;
        const float4 b4 = *(const float4*)&bias[k];
        const float4 f4 = *(const float4*)&Fs[n][k];
        float s[4] = {b4.x + f4.x, b4.y + f4.y, b4.z + f4.z, b4.w + f4.w};
        #pragma unroll
        for (int j = 0; j < 4; ++j) {
            const float sj = s[j];
            const float mnew = fmaxf(mx, sj);
            l = l * __expf(mx - mnew) + __expf(sj - mnew);
            mx = mnew;
            sd = (k + j == n) ? sj : sd;
        }
    }
    redM[t] = mx; redL[t] = l; redD[t] = sd;
    __syncthreads();
    if (t < 128) {
        const float m0 = redM[t],       l0 = redL[t],       d0 = redD[t];
        const float m1 = redM[t + 128], l1 = redL[t + 128], d1 = redD[t + 128];
        const float M  = fmaxf(m0, m1);
        const float L  = l0 * __expf(m0 - M) + l1 * __expf(m1 - M);
        const float sdiag = (t < 64) ? d0 : d1;     // k==n lives in half n/64
        out[b * N_REL + t] = __expf(sdiag - M) / L;
    }
}

// ---------------------------------------------------------------------------
extern "C" void kernel_launch(void* const* d_in, const int* in_sizes, int n_in,
                              void* d_out, int out_size, void* d_ws, size_t ws_size,
                              hipStream_t stream) {
    const float* rep   = (const float*)d_in[0];
    const float* W     = (const float*)d_in[1];
    const float* bias  = (const float*)d_in[2];
    const int*   scope = (const int*)d_in[3];

    const int nsum    = in_sizes[0] / D_DIM;
    const int strips  = (nsum + 15) >> 4;
    const int hstride = strips * 16 * N_REL;     // floats per partial buffer

    unsigned* Bfrag = (unsigned*)d_ws;                       // 393216 B
    float*    Hp    = (float*)((char*)d_ws + 393216);        // NCHUNK * hstride fp32

    build_bfrag<<<48, 256, 0, stream>>>(W, Bfrag);
    h_gemm<<<dim3(strips, NCHUNK), 64, 0, stream>>>(
        rep, (const unsigned short*)Bfrag, Hp, nsum, hstride);
    bag_out<<<B_BAGS, 256, 0, stream>>>(Hp, hstride, bias, scope, (float*)d_out);
}